// Round 3
// baseline (200.443 us; speedup 1.0000x reference)
//
#include <hip/hip_runtime.h>

// ComplexMixture: B=32, S=8192, D=64, fp32 in/out.
// out_real = (R^T R + I^T I)/S   [B,64,64]  (symmetric)
// out_imag = (R^T I - (R^T I)^T)/S          (antisymmetric)
// R5: single fused kernel. Barrier-free wave-private pipelines (each wave owns
//     a 128-row seq slice + private 16KB LDS dbuf, computes full 64x64 via
//     Gram symmetry: 4 frags -> 10 MFMAs/k16). Epilogue merges 4 waves in LDS
//     and atomicAdds scaled partials straight into out (no ws, no 2nd kernel).

#define BATCH  32
#define SEQ    8192
#define DD     64
#define CHUNKS 16
#define SCHUNK (SEQ / CHUNKS)   // 512 rows per block
#define WROWS  (SCHUNK / 4)     // 128 rows per wave
#define NST    (WROWS / 32)     // 4 subtiles of 32 rows

typedef __bf16 bf16x8 __attribute__((ext_vector_type(8)));
typedef float  f32x16 __attribute__((ext_vector_type(16)));
typedef float  f32x4  __attribute__((ext_vector_type(4)));

__device__ __forceinline__ unsigned bf16pk(float a, float b) {
  unsigned ua = __builtin_bit_cast(unsigned, a);
  unsigned ub = __builtin_bit_cast(unsigned, b);
  ua = (ua + 0x7fffu + ((ua >> 16) & 1u)) >> 16;   // RNE to bf16
  ub = (ub + 0x7fffu + ((ub >> 16) & 1u)) >> 16;
  return (ua & 0xffffu) | (ub << 16);
}

// Column permutation (uint4 units within a 64-entry row); bank-conflict-free
// for both the 16-lane ds_write groups and the 32-lane ds_read_b128 groups
// (measured 0 conflicts in R4 with identical geometry).
__device__ __forceinline__ int permd(int d) {
  return d ^ ((d >> 3) & 1) ^ (((d >> 4) & 1) << 1);
}

__device__ __forceinline__ void atomAdd(float* p, float v) {
  __hip_atomic_fetch_add(p, v, __ATOMIC_RELAXED, __HIP_MEMORY_SCOPE_AGENT);
}

// stg[wave][buf][mat][kg][entry]: per-wave private double-buffered tile.
// mat 0 = R, mat 1 = I; kg in [0,4) covers rows kg*8..+8 of the 32-row subtile
// as k-contiguous bf16x8; entry = permd(d).  4*2*2*4*64*16B = 64 KB.
__global__ __launch_bounds__(256, 2) void gram_fused(
    const float* __restrict__ R, const float* __restrict__ I,
    float* __restrict__ out)
{
  __shared__ uint4 stg[4][2][2][4][64];
  const int tid  = threadIdx.x;
  const int w    = tid >> 6;
  const int lane = tid & 63;
  const int l31  = lane & 31;
  const int lhi  = lane >> 5;
  const int g4   = lane >> 4;          // 0..3: row-group within subtile
  const int q    = lane & 15;          // float4 column index
  const int b = blockIdx.x & 31;
  const int c = blockIdx.x >> 5;
  const float* Rb = R + (size_t)b * (SEQ * DD);
  const float* Ib = I + (size_t)b * (SEQ * DD);
  const int p0 = permd(l31);
  const int p1 = permd(32 + l31);
  int pw[4];
  #pragma unroll
  for (int cc = 0; cc < 4; ++cc) pw[cc] = permd(q * 4 + cc);

  // accumulators: real quadrants (symmetric: 00,01,11) + imag quadrants (all 4)
  f32x16 r00 = {}, r01 = {}, r11 = {};
  f32x16 i00 = {}, i01 = {}, i10 = {}, i11 = {};

  f32x4 rv[8], iv[8];
  const size_t rbase = (size_t)(c * SCHUNK + w * WROWS + g4 * 8) * DD;

  // issue the 16-load burst for subtile st_ (rows st_*32 .. +32 of this wave)
#define LOADT(st_) do { \
    const f32x4* pR_ = (const f32x4*)(Rb + rbase + (size_t)(st_) * 32 * DD) + q; \
    const f32x4* pI_ = (const f32x4*)(Ib + rbase + (size_t)(st_) * 32 * DD) + q; \
    _Pragma("unroll") \
    for (int j = 0; j < 8; ++j) { rv[j] = pR_[j * 16]; iv[j] = pI_[j * 16]; } \
    asm volatile("" ::: "memory"); \
  } while (0)

  // convert + write into this wave's buffer buf_ (vmcnt waits land here)
#define PACKW(buf_) do { \
    _Pragma("unroll") \
    for (int cc = 0; cc < 4; ++cc) { \
      uint4 qR_, qI_; \
      qR_.x = bf16pk(rv[0][cc], rv[1][cc]); qR_.y = bf16pk(rv[2][cc], rv[3][cc]); \
      qR_.z = bf16pk(rv[4][cc], rv[5][cc]); qR_.w = bf16pk(rv[6][cc], rv[7][cc]); \
      qI_.x = bf16pk(iv[0][cc], iv[1][cc]); qI_.y = bf16pk(iv[2][cc], iv[3][cc]); \
      qI_.z = bf16pk(iv[4][cc], iv[5][cc]); qI_.w = bf16pk(iv[6][cc], iv[7][cc]); \
      stg[w][buf_][0][g4][pw[cc]] = qR_; \
      stg[w][buf_][1][g4][pw[cc]] = qI_; \
    } \
  } while (0)

  LOADT(0);
  PACKW(0);

  #pragma unroll
  for (int st = 0; st < NST; ++st) {
    const int buf = st & 1;
    if (st + 1 < NST) LOADT(st + 1);     // next subtile in flight across MFMA
    #pragma unroll
    for (int ks = 0; ks < 2; ++ks) {
      const int kg = ks * 2 + lhi;
      bf16x8 fR0 = __builtin_bit_cast(bf16x8, stg[w][buf][0][kg][p0]);
      bf16x8 fR1 = __builtin_bit_cast(bf16x8, stg[w][buf][0][kg][p1]);
      bf16x8 fI0 = __builtin_bit_cast(bf16x8, stg[w][buf][1][kg][p0]);
      bf16x8 fI1 = __builtin_bit_cast(bf16x8, stg[w][buf][1][kg][p1]);
      // C[i][j] = sum_k A[k][i]*B[k][j]; i from A's d-range, j from B's.
      r00 = __builtin_amdgcn_mfma_f32_32x32x16_bf16(fR0, fR0, r00, 0, 0, 0);
      r01 = __builtin_amdgcn_mfma_f32_32x32x16_bf16(fR0, fR1, r01, 0, 0, 0);
      r11 = __builtin_amdgcn_mfma_f32_32x32x16_bf16(fR1, fR1, r11, 0, 0, 0);
      i00 = __builtin_amdgcn_mfma_f32_32x32x16_bf16(fR0, fI0, i00, 0, 0, 0);
      i01 = __builtin_amdgcn_mfma_f32_32x32x16_bf16(fR0, fI1, i01, 0, 0, 0);
      i10 = __builtin_amdgcn_mfma_f32_32x32x16_bf16(fR1, fI0, i10, 0, 0, 0);
      i11 = __builtin_amdgcn_mfma_f32_32x32x16_bf16(fR1, fI1, i11, 0, 0, 0);
      r00 = __builtin_amdgcn_mfma_f32_32x32x16_bf16(fI0, fI0, r00, 0, 0, 0);
      r01 = __builtin_amdgcn_mfma_f32_32x32x16_bf16(fI0, fI1, r01, 0, 0, 0);
      r11 = __builtin_amdgcn_mfma_f32_32x32x16_bf16(fI1, fI1, r11, 0, 0, 0);
    }
    if (st + 1 < NST) PACKW(buf ^ 1);    // other buffer; wave-private, no barrier
  }
#undef LOADT
#undef PACKW

  // ---- epilogue: merge 4 waves in LDS, atomicAdd scaled result into out ----
  __syncthreads();                        // all waves done with private staging
  float* sc = (float*)stg;
  const float inv = 1.0f / (float)SEQ;
  float* outR = out + (size_t)b * 4096;
  float* outM = out + 131072 + (size_t)b * 4096;

  // C/D layout: value r -> (p = (r&3)+8*(r>>2)+4*lhi, q = l31) within quadrant.
  // quad slot = [32][33] floats (1056); wave stride padded +8 to offset banks.
#define WRQ(stride_, t_, acc_) do { \
    _Pragma("unroll") \
    for (int r = 0; r < 16; ++r) { \
      const int p_ = (r & 3) + 8 * (r >> 2) + 4 * lhi; \
      sc[w * (stride_) + (t_) * 1056 + p_ * 33 + l31] = acc_[r]; \
    } \
  } while (0)

  // P1: real quadrants r00, r01, r11  (wave stride 3*1056+8 = 3176; 50.8 KB)
  WRQ(3176, 0, r00); WRQ(3176, 1, r01); WRQ(3176, 2, r11);
  __syncthreads();
  #pragma unroll
  for (int kk = 0; kk < 12; ++kk) {
    const int e = tid + 256 * kk;          // 3072 elements
    const int t = e >> 10, idx = e & 1023, p = idx >> 5, qq = idx & 31;
    float v = 0.f;
    #pragma unroll
    for (int wv = 0; wv < 4; ++wv) v += sc[wv * 3176 + t * 1056 + p * 33 + qq];
    v *= inv;
    if (t == 0)      atomAdd(&outR[p * 64 + qq], v);
    else if (t == 1) { atomAdd(&outR[p * 64 + 32 + qq], v);
                       atomAdd(&outR[(32 + qq) * 64 + p], v); }   // symmetric
    else             atomAdd(&outR[(32 + p) * 64 + 32 + qq], v);
  }
  __syncthreads();

  // P2: imag off-diagonal: i01 (t=0), i10 (t=1)  (stride 2*1056+8 = 2120)
  WRQ(2120, 0, i01); WRQ(2120, 1, i10);
  __syncthreads();
  #pragma unroll
  for (int kk = 0; kk < 4; ++kk) {
    const int e = tid + 256 * kk;          // 1024 elements
    const int p = e >> 5, qq = e & 31;
    float v01 = 0.f, v10 = 0.f;
    #pragma unroll
    for (int wv = 0; wv < 4; ++wv) {
      v01 += sc[wv * 2120 + 0 * 1056 + p * 33 + qq];
      v10 += sc[wv * 2120 + 1 * 1056 + qq * 33 + p];   // I10[q][p]
    }
    const float m = (v01 - v10) * inv;     // M[p][32+q]
    atomAdd(&outM[p * 64 + 32 + qq],  m);
    atomAdd(&outM[(32 + qq) * 64 + p], -m);            // M10 = -M01^T
  }
  __syncthreads();

  // P3: imag diagonal: i00 (t=0), i11 (t=1)
  WRQ(2120, 0, i00); WRQ(2120, 1, i11);
  __syncthreads();
  #pragma unroll
  for (int kk = 0; kk < 8; ++kk) {
    const int e = tid + 256 * kk;          // 2048 elements
    const int t = e >> 10, idx = e & 1023, p = idx >> 5, qq = idx & 31;
    float a = 0.f, bt = 0.f;
    #pragma unroll
    for (int wv = 0; wv < 4; ++wv) {
      a  += sc[wv * 2120 + t * 1056 + p * 33 + qq];
      bt += sc[wv * 2120 + t * 1056 + qq * 33 + p];
    }
    const float m = (a - bt) * inv;
    if (t == 0) atomAdd(&outM[p * 64 + qq], m);
    else        atomAdd(&outM[(32 + p) * 64 + 32 + qq], m);
  }
#undef WRQ
}

extern "C" void kernel_launch(void* const* d_in, const int* in_sizes, int n_in,
                              void* d_out, int out_size, void* d_ws, size_t ws_size,
                              hipStream_t stream) {
  const float* R = (const float*)d_in[0];
  const float* I = (const float*)d_in[1];
  float* out = (float*)d_out;
  (void)d_ws; (void)ws_size;

  hipMemsetAsync(d_out, 0, (size_t)out_size, stream);   // capture-safe stream op
  gram_fused<<<BATCH * CHUNKS, 256, 0, stream>>>(R, I, out);
}

// Round 4
// 158.289 us; speedup vs baseline: 1.2663x; 1.2663x over previous
//
#include <hip/hip_runtime.h>

// ComplexMixture: B=32, S=8192, D=64, fp32 in/out.
// out_real = (R^T R + I^T I)/S   [B,64,64]  (symmetric)
// out_imag = (R^T I - (R^T I)^T)/S          (antisymmetric)
// R6: TLP fix. 1024 blocks (CHUNKS=32), 32 KB LDS/block, 4 blocks/CU,
//     launch_bounds(256,4). R4-style quadrant split (2 accs = 32 VGPR/wave),
//     mat-split staging (waves 0-1 load R, 2-3 load I; 32 staging regs).
//     Atomic-output epilogue (no ws, no reduce kernel).

#define BATCH  32
#define SEQ    8192
#define DD     64
#define CHUNKS 32
#define SCHUNK (SEQ / CHUNKS)   // 256 rows per block
#define TR     64               // rows per tile
#define NIT    (SCHUNK / TR)    // 4 tiles (even)

typedef __bf16 bf16x8 __attribute__((ext_vector_type(8)));
typedef float  f32x16 __attribute__((ext_vector_type(16)));
typedef float  f32x4  __attribute__((ext_vector_type(4)));

__device__ __forceinline__ unsigned bf16pk(float a, float b) {
  unsigned ua = __builtin_bit_cast(unsigned, a);
  unsigned ub = __builtin_bit_cast(unsigned, b);
  ua = (ua + 0x7fffu + ((ua >> 16) & 1u)) >> 16;   // RNE to bf16
  ub = (ub + 0x7fffu + ((ub >> 16) & 1u)) >> 16;
  return (ua & 0xffffu) | (ub << 16);
}

// Column permutation (uint4 units within a 64-entry row); bank-conflict-free
// for both 16-lane ds_write groups and 32-lane ds_read_b128 fragment reads
// (0 conflicts measured in R4/R5 with identical geometry).
__device__ __forceinline__ int permd(int d) {
  return d ^ ((d >> 3) & 1) ^ (((d >> 4) & 1) << 1);
}

__device__ __forceinline__ void atomAdd(float* p, float v) {
  __hip_atomic_fetch_add(p, v, __ATOMIC_RELAXED, __HIP_MEMORY_SCOPE_AGENT);
}

// lds[buf][mat][kg][entry]: double-buffered 64-row tile, mat 0=R 1=I.
// Row kg holds s-rows kg*8..+8 as k-contiguous bf16x8; entry = permd(d).
// 2*2*8*64*16B = 32 KB -> 4 blocks/CU.
__global__ __launch_bounds__(256, 4) void gram_fused(
    const float* __restrict__ R, const float* __restrict__ I,
    float* __restrict__ out)
{
  __shared__ uint4 lds[2][2][8][64];
  const int tid  = threadIdx.x;
  const int wave = tid >> 6;
  const int lane = tid & 63;
  const int l31  = lane & 31;
  const int lhi  = lane >> 5;
  const int mat  = tid >> 7;            // waves 0-1: R, waves 2-3: I
  const int g    = (tid >> 4) & 7;      // row-group (rows g*8..+8 of tile)
  const int q    = tid & 15;            // float4 column index
  const int b = blockIdx.x & 31;
  const int c = blockIdx.x >> 5;
  const float* Mb = (mat ? I : R) + (size_t)b * (SEQ * DD);
  const int m0 = (wave >> 1) * 32;      // output quadrant of this wave
  const int n0 = (wave & 1) * 32;
  const int pa = permd(m0 + l31);
  const int pb = permd(n0 + l31);
  int pw[4];
  #pragma unroll
  for (int cc = 0; cc < 4; ++cc) pw[cc] = permd(q * 4 + cc);

  f32x16 accR = {};   // rr + ii quadrant (m0,n0)
  f32x16 accI = {};   // ri quadrant (m0,n0)

  f32x4 v[8];         // 32 staging regs (one matrix, 8 rows x 4 cols)
  const size_t rbase = (size_t)(c * SCHUNK + g * 8) * DD;

  // issue the 8-load burst for tile t_ (this thread's 8 rows x 4 cols)
#define LOADT(t_) do { \
    const f32x4* p_ = (const f32x4*)(Mb + rbase + (size_t)(t_) * TR * DD) + q; \
    _Pragma("unroll") \
    for (int j = 0; j < 8; ++j) v[j] = p_[j * 16]; \
    asm volatile("" ::: "memory"); \
  } while (0)

  // convert + write into buffer buf_ (vmcnt waits land here, after MFMA)
#define PACKW(buf_) do { \
    _Pragma("unroll") \
    for (int cc = 0; cc < 4; ++cc) { \
      uint4 u_; \
      u_.x = bf16pk(v[0][cc], v[1][cc]); u_.y = bf16pk(v[2][cc], v[3][cc]); \
      u_.z = bf16pk(v[4][cc], v[5][cc]); u_.w = bf16pk(v[6][cc], v[7][cc]); \
      lds[buf_][mat][g][pw[cc]] = u_; \
    } \
  } while (0)

  // barrier with no vmcnt drain; sched_barrier both sides (rule #18)
#define TILEBAR() do { \
    __builtin_amdgcn_sched_barrier(0); \
    asm volatile("s_waitcnt lgkmcnt(0)" ::: "memory"); \
    __builtin_amdgcn_s_barrier(); \
    __builtin_amdgcn_sched_barrier(0); \
  } while (0)

  LOADT(0);
  PACKW(0);
  TILEBAR();

  #pragma unroll
  for (int it = 0; it < NIT; ++it) {
    const int buf = it & 1;
    if (it + 1 < NIT) LOADT(it + 1);    // next tile in flight across MFMA
    #pragma unroll
    for (int ks = 0; ks < TR / 16; ++ks) {
      const int kg = ks * 2 + lhi;
      bf16x8 aR = __builtin_bit_cast(bf16x8, lds[buf][0][kg][pa]);
      bf16x8 bR = __builtin_bit_cast(bf16x8, lds[buf][0][kg][pb]);
      bf16x8 aI = __builtin_bit_cast(bf16x8, lds[buf][1][kg][pa]);
      bf16x8 bI = __builtin_bit_cast(bf16x8, lds[buf][1][kg][pb]);
      accR = __builtin_amdgcn_mfma_f32_32x32x16_bf16(aR, bR, accR, 0, 0, 0);
      accR = __builtin_amdgcn_mfma_f32_32x32x16_bf16(aI, bI, accR, 0, 0, 0);
      accI = __builtin_amdgcn_mfma_f32_32x32x16_bf16(aR, bI, accI, 0, 0, 0);
    }
    if (it + 1 < NIT) {
      PACKW(buf ^ 1);                   // other buffer; readers sync'd by bar
      TILEBAR();                        // single barrier per tile
    }
  }
#undef LOADT
#undef PACKW
#undef TILEBAR

  // ---- epilogue: atomic-accumulate scaled partials into out ----
  const float inv = 1.0f / (float)SEQ;
  float* outR = out + (size_t)b * 4096;
  float* outM = out + 131072 + (size_t)b * 4096;
  const int jj = n0 + l31;

  // real: direct from regs (full 64x64 covered by the 4 quadrants)
  #pragma unroll
  for (int r = 0; r < 16; ++r) {
    const int i = m0 + (r & 3) + 8 * (r >> 2) + 4 * lhi;
    atomAdd(&outR[i * 64 + jj], accR[r] * inv);
  }

  // imag: antisymmetrize via LDS scratch (64x65 f32 = 16.6 KB), then atomics.
  __syncthreads();                      // all MFMA reads done before overwrite
  float* sc = (float*)lds;
  #pragma unroll
  for (int r = 0; r < 16; ++r) {
    const int i = m0 + (r & 3) + 8 * (r >> 2) + 4 * lhi;
    sc[i * 65 + jj] = accI[r];
  }
  __syncthreads();
  #pragma unroll
  for (int r = 0; r < 16; ++r) {
    const int i = m0 + (r & 3) + 8 * (r >> 2) + 4 * lhi;
    const float m = (sc[i * 65 + jj] - sc[jj * 65 + i]) * inv;
    atomAdd(&outM[i * 64 + jj], m);
  }
}

extern "C" void kernel_launch(void* const* d_in, const int* in_sizes, int n_in,
                              void* d_out, int out_size, void* d_ws, size_t ws_size,
                              hipStream_t stream) {
  const float* R = (const float*)d_in[0];
  const float* I = (const float*)d_in[1];
  float* out = (float*)d_out;
  (void)d_ws; (void)ws_size;

  hipMemsetAsync(d_out, 0, (size_t)out_size, stream);   // capture-safe
  gram_fused<<<BATCH * CHUNKS, 256, 0, stream>>>(R, I, out);
}

// Round 5
// 149.124 us; speedup vs baseline: 1.3441x; 1.0615x over previous
//
#include <hip/hip_runtime.h>

// ComplexMixture: B=32, S=8192, D=64, fp32 in/out.
// out_real = (R^T R + I^T I)/S   [B,64,64]  (symmetric)
// out_imag = (R^T I - (R^T I)^T)/S          (antisymmetric)
// R7: convoy-breaker. Prefetch depth 3 (3 reg bursts in flight, waits only on
//     the oldest -> vmcnt never drains in-loop), quad-buffered LDS (64 KB),
//     CHUNKS=16 -> 512 blocks = exactly 2/CU, NIT=8. R6 quadrant split
//     (2 accs/wave), mat-split staging, atomic-output epilogue.

#define BATCH  32
#define SEQ    8192
#define DD     64
#define CHUNKS 16
#define SCHUNK (SEQ / CHUNKS)   // 512 rows per block
#define TR     64               // rows per tile
#define NIT    (SCHUNK / TR)    // 8 tiles

typedef __bf16 bf16x8 __attribute__((ext_vector_type(8)));
typedef float  f32x16 __attribute__((ext_vector_type(16)));
typedef float  f32x4  __attribute__((ext_vector_type(4)));

__device__ __forceinline__ unsigned bf16pk(float a, float b) {
  unsigned ua = __builtin_bit_cast(unsigned, a);
  unsigned ub = __builtin_bit_cast(unsigned, b);
  ua = (ua + 0x7fffu + ((ua >> 16) & 1u)) >> 16;   // RNE to bf16
  ub = (ub + 0x7fffu + ((ub >> 16) & 1u)) >> 16;
  return (ua & 0xffffu) | (ub << 16);
}

// Column permutation (uint4 units within a 64-entry row); bank-conflict-free
// for both 16-lane ds_write groups and 32-lane ds_read_b128 fragment reads
// (0 conflicts measured R4/R5/R6 with identical geometry).
__device__ __forceinline__ int permd(int d) {
  return d ^ ((d >> 3) & 1) ^ (((d >> 4) & 1) << 1);
}

__device__ __forceinline__ void atomAdd(float* p, float v) {
  __hip_atomic_fetch_add(p, v, __ATOMIC_RELAXED, __HIP_MEMORY_SCOPE_AGENT);
}

// lds[buf][mat][kg][entry]: quad-buffered 64-row tile, mat 0=R 1=I.
// Row kg holds s-rows kg*8..+8 as k-contiguous bf16x8; entry = permd(d).
// 4*2*8*64*16B = 64 KB -> 2 blocks/CU (grid gives exactly 2/CU anyway).
__global__ __launch_bounds__(256, 2) void gram_fused(
    const float* __restrict__ R, const float* __restrict__ I,
    float* __restrict__ out)
{
  __shared__ uint4 lds[4][2][8][64];
  const int tid  = threadIdx.x;
  const int wave = tid >> 6;
  const int lane = tid & 63;
  const int l31  = lane & 31;
  const int lhi  = lane >> 5;
  const int mat  = tid >> 7;            // waves 0-1 stage R, waves 2-3 stage I
  const int g    = (tid >> 4) & 7;      // row-group (rows g*8..+8 of tile)
  const int q    = tid & 15;            // float4 column index
  const int b = blockIdx.x & 31;
  const int c = blockIdx.x >> 5;
  const float* Mb = (mat ? I : R) + (size_t)b * (SEQ * DD);
  const int m0 = (wave >> 1) * 32;      // output quadrant of this wave
  const int n0 = (wave & 1) * 32;
  const int pa = permd(m0 + l31);
  const int pb = permd(n0 + l31);
  int pw[4];
  #pragma unroll
  for (int cc = 0; cc < 4; ++cc) pw[cc] = permd(q * 4 + cc);

  f32x16 accR = {};   // rr + ii quadrant (m0,n0)
  f32x16 accI = {};   // ri quadrant (m0,n0)

  f32x4 v[3][8];      // 96 staging regs: 3 bursts in flight
  const size_t rbase = (size_t)(c * SCHUNK + g * 8) * DD;

  // issue the 8-load burst for tile t_ into regset rs_
#define LOADT(t_, rs_) do { \
    const f32x4* p_ = (const f32x4*)(Mb + rbase + (size_t)(t_) * TR * DD) + q; \
    _Pragma("unroll") \
    for (int j = 0; j < 8; ++j) v[rs_][j] = p_[j * 16]; \
    asm volatile("" ::: "memory"); \
  } while (0)

  // convert + write regset rs_ into buffer buf_ (compiler inserts a counted
  // vmcnt here: only the oldest burst is waited, 16 newer stay outstanding)
#define PACKW(buf_, rs_) do { \
    _Pragma("unroll") \
    for (int cc = 0; cc < 4; ++cc) { \
      uint4 u_; \
      u_.x = bf16pk(v[rs_][0][cc], v[rs_][1][cc]); \
      u_.y = bf16pk(v[rs_][2][cc], v[rs_][3][cc]); \
      u_.z = bf16pk(v[rs_][4][cc], v[rs_][5][cc]); \
      u_.w = bf16pk(v[rs_][6][cc], v[rs_][7][cc]); \
      lds[buf_][mat][g][pw[cc]] = u_; \
    } \
  } while (0)

  // barrier with no vmcnt drain; sched_barrier both sides (rule #18)
#define TILEBAR() do { \
    __builtin_amdgcn_sched_barrier(0); \
    asm volatile("s_waitcnt lgkmcnt(0)" ::: "memory"); \
    __builtin_amdgcn_s_barrier(); \
    __builtin_amdgcn_sched_barrier(0); \
  } while (0)

  // prologue: 3 bursts in flight, pack tile 0
  LOADT(0, 0);
  LOADT(1, 1);
  LOADT(2, 2);
  PACKW(0, 0);
  TILEBAR();

  #pragma unroll
  for (int t = 0; t < NIT; ++t) {
    if (t + 3 < NIT) LOADT(t + 3, (t + 3) % 3);   // keep 3 bursts outstanding
    const int buf = t & 3;
    #pragma unroll
    for (int ks = 0; ks < TR / 16; ++ks) {
      const int kg = ks * 2 + lhi;
      bf16x8 aR = __builtin_bit_cast(bf16x8, lds[buf][0][kg][pa]);
      bf16x8 bR = __builtin_bit_cast(bf16x8, lds[buf][0][kg][pb]);
      bf16x8 aI = __builtin_bit_cast(bf16x8, lds[buf][1][kg][pa]);
      bf16x8 bI = __builtin_bit_cast(bf16x8, lds[buf][1][kg][pb]);
      accR = __builtin_amdgcn_mfma_f32_32x32x16_bf16(aR, bR, accR, 0, 0, 0);
      accR = __builtin_amdgcn_mfma_f32_32x32x16_bf16(aI, bI, accR, 0, 0, 0);
      accI = __builtin_amdgcn_mfma_f32_32x32x16_bf16(aR, bI, accI, 0, 0, 0);
    }
    if (t + 1 < NIT) {
      PACKW((t + 1) & 3, (t + 1) % 3);  // buffer (t+1)%4: last read 3 tiles ago
      TILEBAR();                        // single barrier per tile
    }
  }
#undef LOADT
#undef PACKW
#undef TILEBAR

  // ---- epilogue: atomic-accumulate scaled partials into out ----
  const float inv = 1.0f / (float)SEQ;
  float* outR = out + (size_t)b * 4096;
  float* outM = out + 131072 + (size_t)b * 4096;
  const int jj = n0 + l31;

  // real: direct from regs (full 64x64 covered by the 4 quadrants)
  #pragma unroll
  for (int r = 0; r < 16; ++r) {
    const int i = m0 + (r & 3) + 8 * (r >> 2) + 4 * lhi;
    atomAdd(&outR[i * 64 + jj], accR[r] * inv);
  }

  // imag: antisymmetrize via LDS scratch (64x65 f32 = 16.6 KB), then atomics.
  __syncthreads();                      // all MFMA reads done before overwrite
  float* sc = (float*)lds;
  #pragma unroll
  for (int r = 0; r < 16; ++r) {
    const int i = m0 + (r & 3) + 8 * (r >> 2) + 4 * lhi;
    sc[i * 65 + jj] = accI[r];
  }
  __syncthreads();
  #pragma unroll
  for (int r = 0; r < 16; ++r) {
    const int i = m0 + (r & 3) + 8 * (r >> 2) + 4 * lhi;
    const float m = (sc[i * 65 + jj] - sc[jj * 65 + i]) * inv;
    atomAdd(&outM[i * 64 + jj], m);
  }
}

extern "C" void kernel_launch(void* const* d_in, const int* in_sizes, int n_in,
                              void* d_out, int out_size, void* d_ws, size_t ws_size,
                              hipStream_t stream) {
  const float* R = (const float*)d_in[0];
  const float* I = (const float*)d_in[1];
  float* out = (float*)d_out;
  (void)d_ws; (void)ws_size;

  hipMemsetAsync(d_out, 0, (size_t)out_size, stream);   // capture-safe
  gram_fused<<<BATCH * CHUNKS, 256, 0, stream>>>(R, I, out);
}